// Round 1
// baseline (463.607 us; speedup 1.0000x reference)
//
#include <hip/hip_runtime.h>

#define N_LOC 100000
#define N_EVT 100000
#define N_EDGE 1600000

// ---------------------------------------------------------------------------
// K1: evt_x = relu(evt_feat @ W_evt + b_evt)     [N_EVT x 64]
// One wave per event row (grid-stride). W column held in 128 VGPRs per lane.
// Row staged to per-wave LDS, consumed as float4 broadcasts (same-addr reads).
// ---------------------------------------------------------------------------
__global__ __launch_bounds__(256) void k_evt(const float* __restrict__ feat,
                                             const float* __restrict__ W,
                                             const float* __restrict__ b,
                                             float* __restrict__ out, int n) {
    __shared__ float srow[4][128];
    const int lane = threadIdx.x & 63;
    const int w = threadIdx.x >> 6;
    float wreg[128];
#pragma unroll
    for (int j = 0; j < 128; ++j) wreg[j] = W[j * 64 + lane];
    const float bias = b[lane];
    const int wid = blockIdx.x * 4 + w;
    const int nw = gridDim.x * 4;
    for (int e = wid; e < n; e += nw) {
        const float4* rp = (const float4*)(feat + (size_t)e * 128);
        if (lane < 32) ((float4*)srow[w])[lane] = rp[lane];
        const float4* s4 = (const float4*)srow[w];
        float acc = bias;
#pragma unroll
        for (int j4 = 0; j4 < 32; ++j4) {
            float4 x = s4[j4];
            acc = fmaf(x.x, wreg[4 * j4 + 0], acc);
            acc = fmaf(x.y, wreg[4 * j4 + 1], acc);
            acc = fmaf(x.z, wreg[4 * j4 + 2], acc);
            acc = fmaf(x.w, wreg[4 * j4 + 3], acc);
        }
        out[(size_t)e * 64 + lane] = fmaxf(acc, 0.0f);
    }
}

// ---------------------------------------------------------------------------
// K2: loc_x = relu([loc_feat || emb[qid]] @ W_loc + b_loc)   [N_LOC x 64]
// ---------------------------------------------------------------------------
__global__ __launch_bounds__(256) void k_loc(const float* __restrict__ feat,
                                             const int* __restrict__ qid,
                                             const float* __restrict__ emb,
                                             const float* __restrict__ W,
                                             const float* __restrict__ b,
                                             float* __restrict__ out, int n) {
    __shared__ float srow[4][144];
    const int lane = threadIdx.x & 63;
    const int w = threadIdx.x >> 6;
    float wreg[144];
#pragma unroll
    for (int j = 0; j < 144; ++j) wreg[j] = W[j * 64 + lane];
    const float bias = b[lane];
    const int wid = blockIdx.x * 4 + w;
    const int nw = gridDim.x * 4;
    for (int e = wid; e < n; e += nw) {
        const float4* rp = (const float4*)(feat + (size_t)e * 128);
        if (lane < 32) ((float4*)srow[w])[lane] = rp[lane];
        int q = qid[e];
        if (lane < 4)
            ((float4*)(srow[w] + 128))[lane] = ((const float4*)(emb + (size_t)q * 16))[lane];
        const float4* s4 = (const float4*)srow[w];
        float acc = bias;
#pragma unroll
        for (int j4 = 0; j4 < 36; ++j4) {
            float4 x = s4[j4];
            acc = fmaf(x.x, wreg[4 * j4 + 0], acc);
            acc = fmaf(x.y, wreg[4 * j4 + 1], acc);
            acc = fmaf(x.z, wreg[4 * j4 + 2], acc);
            acc = fmaf(x.w, wreg[4 * j4 + 3], acc);
        }
        out[(size_t)e * 64 + lane] = fmaxf(acc, 0.0f);
    }
}

// ---------------------------------------------------------------------------
// CSR build: histogram -> exclusive scan -> fill
// ---------------------------------------------------------------------------
__global__ __launch_bounds__(256) void k_hist(const int* __restrict__ dst,
                                              int* __restrict__ deg, int n) {
    int i = blockIdx.x * 256 + threadIdx.x;
    if (i < n) atomicAdd(&deg[dst[i]], 1);
}

__global__ __launch_bounds__(256) void k_scan1(const int* __restrict__ deg,
                                               int* __restrict__ row_ex,
                                               int* __restrict__ partials, int n) {
    __shared__ int sd[256];
    const int t = threadIdx.x;
    const int base = blockIdx.x * 1024 + t * 4;
    int v0 = (base + 0 < n) ? deg[base + 0] : 0;
    int v1 = (base + 1 < n) ? deg[base + 1] : 0;
    int v2 = (base + 2 < n) ? deg[base + 2] : 0;
    int v3 = (base + 3 < n) ? deg[base + 3] : 0;
    int tot = v0 + v1 + v2 + v3;
    sd[t] = tot;
    __syncthreads();
    for (int off = 1; off < 256; off <<= 1) {
        int x = (t >= off) ? sd[t - off] : 0;
        __syncthreads();
        sd[t] += x;
        __syncthreads();
    }
    int excl = sd[t] - tot;
    if (t == 255) partials[blockIdx.x] = sd[255];
    if (base + 0 < n) row_ex[base + 0] = excl;
    if (base + 1 < n) row_ex[base + 1] = excl + v0;
    if (base + 2 < n) row_ex[base + 2] = excl + v0 + v1;
    if (base + 3 < n) row_ex[base + 3] = excl + v0 + v1 + v2;
}

__global__ __launch_bounds__(128) void k_scan2(int* __restrict__ partials, int nchunk) {
    __shared__ int sd[128];
    const int t = threadIdx.x;
    int v = (t < nchunk) ? partials[t] : 0;
    sd[t] = v;
    __syncthreads();
    for (int off = 1; off < 128; off <<= 1) {
        int x = (t >= off) ? sd[t - off] : 0;
        __syncthreads();
        sd[t] += x;
        __syncthreads();
    }
    if (t < nchunk) partials[t] = sd[t] - v;
}

__global__ __launch_bounds__(256) void k_scan3(int* __restrict__ row_ex,
                                               const int* __restrict__ partials,
                                               int* __restrict__ cursor, int n) {
    int i = blockIdx.x * 256 + threadIdx.x;
    if (i < n) {
        int v = row_ex[i] + partials[i >> 10];
        row_ex[i] = v;
        cursor[i] = v;
    }
}

__global__ __launch_bounds__(256) void k_fill(const int* __restrict__ ei,
                                              int* __restrict__ cursor,
                                              int* __restrict__ csr_src, int n) {
    int i = blockIdx.x * 256 + threadIdx.x;
    if (i < n) {
        int s = ei[i];
        int d = ei[n + i];
        int pos = atomicAdd(&cursor[d], 1);
        csr_src[pos] = s;
    }
}

// ---------------------------------------------------------------------------
// K4: mean[loc] = (sum over neighbors of evt_x[src]) / max(cnt,1)
// One wave per loc; lane = channel. Unroll-by-4 for memory ILP.
// ---------------------------------------------------------------------------
__global__ __launch_bounds__(256) void k_aggr(const float* __restrict__ evt_x,
                                              const int* __restrict__ row_ex,
                                              const int* __restrict__ deg,
                                              const int* __restrict__ csr_src,
                                              float* __restrict__ meanb, int n) {
    const int lane = threadIdx.x & 63;
    const int wid = (blockIdx.x * 256 + threadIdx.x) >> 6;
    if (wid >= n) return;
    const int beg = row_ex[wid];
    const int cnt = deg[wid];
    float acc = 0.0f;
    int i = 0;
    for (; i + 4 <= cnt; i += 4) {
        int s0 = csr_src[beg + i + 0];
        int s1 = csr_src[beg + i + 1];
        int s2 = csr_src[beg + i + 2];
        int s3 = csr_src[beg + i + 3];
        float a0 = evt_x[(size_t)s0 * 64 + lane];
        float a1 = evt_x[(size_t)s1 * 64 + lane];
        float a2 = evt_x[(size_t)s2 * 64 + lane];
        float a3 = evt_x[(size_t)s3 * 64 + lane];
        acc += a0 + a1 + a2 + a3;
    }
    for (; i < cnt; ++i) acc += evt_x[(size_t)csr_src[beg + i] * 64 + lane];
    float c = (cnt > 0) ? (float)cnt : 1.0f;
    meanb[(size_t)wid * 64 + lane] = acc / c;
}

// ---------------------------------------------------------------------------
// K5: x2 = relu(mean @ W_l + b_l + loc_x @ W_r); h = relu(x2 @ W_h1 + b_h1);
//     out = h @ W_h2 + b_h2
// One wave per loc. W_l/W_r columns in registers; broadcasts via per-wave LDS.
// ---------------------------------------------------------------------------
__global__ __launch_bounds__(256) void k_comb(const float* __restrict__ meanb,
                                              const float* __restrict__ locx,
                                              const float* __restrict__ W_l,
                                              const float* __restrict__ b_l,
                                              const float* __restrict__ W_r,
                                              const float* __restrict__ W_h1,
                                              const float* __restrict__ b_h1,
                                              const float* __restrict__ W_h2,
                                              const float* __restrict__ b_h2,
                                              float* __restrict__ out, int n) {
    __shared__ float sWh1[64 * 32];
    __shared__ float sWh2[32];
    __shared__ float sm[4][64];
    __shared__ float sx[4][64];
    const int t = threadIdx.x;
    for (int i = t; i < 2048; i += 256) sWh1[i] = W_h1[i];
    if (t < 32) sWh2[t] = W_h2[t];
    const int lane = t & 63;
    const int w = t >> 6;
    float wl[64], wr[64];
#pragma unroll
    for (int j = 0; j < 64; ++j) {
        wl[j] = W_l[j * 64 + lane];
        wr[j] = W_r[j * 64 + lane];
    }
    const float bl = b_l[lane];
    const int kk = lane & 31;
    const float bh1 = b_h1[kk];
    const float bh2 = b_h2[0];
    __syncthreads();
    const int wid0 = blockIdx.x * 4 + w;
    const int nw = gridDim.x * 4;
    for (int loc = wid0; loc < n; loc += nw) {
        float mv = meanb[(size_t)loc * 64 + lane];
        float xv = locx[(size_t)loc * 64 + lane];
        sm[w][lane] = mv;
        sx[w][lane] = xv;
        const float4* m4 = (const float4*)sm[w];
        const float4* x4 = (const float4*)sx[w];
        float o = bl;
#pragma unroll
        for (int j4 = 0; j4 < 16; ++j4) {
            float4 a = m4[j4];
            float4 c = x4[j4];
            o = fmaf(a.x, wl[4 * j4 + 0], o); o = fmaf(c.x, wr[4 * j4 + 0], o);
            o = fmaf(a.y, wl[4 * j4 + 1], o); o = fmaf(c.y, wr[4 * j4 + 1], o);
            o = fmaf(a.z, wl[4 * j4 + 2], o); o = fmaf(c.z, wr[4 * j4 + 2], o);
            o = fmaf(a.w, wl[4 * j4 + 3], o); o = fmaf(c.w, wr[4 * j4 + 3], o);
        }
        o = fmaxf(o, 0.0f);
        sx[w][lane] = o;  // same-wave LDS ops are in-order: safe without barrier
        float hv = bh1;
#pragma unroll
        for (int j4 = 0; j4 < 16; ++j4) {
            float4 a = x4[j4];
            hv = fmaf(a.x, sWh1[(4 * j4 + 0) * 32 + kk], hv);
            hv = fmaf(a.y, sWh1[(4 * j4 + 1) * 32 + kk], hv);
            hv = fmaf(a.z, sWh1[(4 * j4 + 2) * 32 + kk], hv);
            hv = fmaf(a.w, sWh1[(4 * j4 + 3) * 32 + kk], hv);
        }
        hv = fmaxf(hv, 0.0f) * sWh2[kk];
#pragma unroll
        for (int m = 16; m >= 1; m >>= 1) hv += __shfl_xor(hv, m);
        if (lane == 0) out[loc] = hv + bh2;
    }
}

// ---------------------------------------------------------------------------
extern "C" void kernel_launch(void* const* d_in, const int* in_sizes, int n_in,
                              void* d_out, int out_size, void* d_ws, size_t ws_size,
                              hipStream_t stream) {
    const float* loc_feat = (const float*)d_in[0];
    const float* evt_feat = (const float*)d_in[1];
    const int*   qid      = (const int*)d_in[2];
    const int*   ei       = (const int*)d_in[3];
    const float* emb      = (const float*)d_in[4];
    const float* W_loc    = (const float*)d_in[5];
    const float* b_loc    = (const float*)d_in[6];
    const float* W_evt    = (const float*)d_in[7];
    const float* b_evt    = (const float*)d_in[8];
    const float* W_l      = (const float*)d_in[9];
    const float* b_l      = (const float*)d_in[10];
    const float* W_r      = (const float*)d_in[11];
    const float* W_h1     = (const float*)d_in[12];
    const float* b_h1     = (const float*)d_in[13];
    const float* W_h2     = (const float*)d_in[14];
    const float* b_h2     = (const float*)d_in[15];
    float* out = (float*)d_out;

    char* ws = (char*)d_ws;
    size_t off = 0;
    auto alloc = [&](size_t bytes) -> void* {
        void* p = ws + off;
        off += (bytes + 255) & ~(size_t)255;
        return p;
    };
    float* evt_x   = (float*)alloc((size_t)N_EVT * 64 * 4);
    float* loc_x   = (float*)alloc((size_t)N_LOC * 64 * 4);
    float* meanb   = (float*)alloc((size_t)N_LOC * 64 * 4);
    int*   deg     = (int*)alloc((size_t)N_LOC * 4);
    int*   row_ex  = (int*)alloc((size_t)N_LOC * 4);
    int*   cursor  = (int*)alloc((size_t)N_LOC * 4);
    int*   csr     = (int*)alloc((size_t)N_EDGE * 4);
    int*   partials= (int*)alloc(1024 * 4);
    (void)ws_size; (void)in_sizes; (void)n_in; (void)out_size;

    hipMemsetAsync(deg, 0, (size_t)N_LOC * 4, stream);

    k_evt<<<768, 256, 0, stream>>>(evt_feat, W_evt, b_evt, evt_x, N_EVT);
    k_loc<<<768, 256, 0, stream>>>(loc_feat, qid, emb, W_loc, b_loc, loc_x, N_LOC);
    k_hist<<<(N_EDGE + 255) / 256, 256, 0, stream>>>(ei + N_EDGE, deg, N_EDGE);
    k_scan1<<<(N_LOC + 1023) / 1024, 256, 0, stream>>>(deg, row_ex, partials, N_LOC);
    k_scan2<<<1, 128, 0, stream>>>(partials, (N_LOC + 1023) / 1024);
    k_scan3<<<(N_LOC + 255) / 256, 256, 0, stream>>>(row_ex, partials, cursor, N_LOC);
    k_fill<<<(N_EDGE + 255) / 256, 256, 0, stream>>>(ei, cursor, csr, N_EDGE);
    k_aggr<<<N_LOC / 4, 256, 0, stream>>>(evt_x, row_ex, deg, csr, meanb, N_LOC);
    k_comb<<<768, 256, 0, stream>>>(meanb, loc_x, W_l, b_l, W_r, W_h1, b_h1, W_h2, b_h2, out, N_LOC);
}

// Round 4
// 316.238 us; speedup vs baseline: 1.4660x; 1.4660x over previous
//
#include <hip/hip_runtime.h>

#define N_LOC 100000
#define N_EVT 100000
#define N_EDGE 1600000
#define NB 391        // ceil(N_LOC/256) buckets of 256 dst values
#define BCAP 5120     // bucket capacity: avg 4096 + 16 sigma
#define TILE 4096     // edges per k_bin block (256 thr x 16)

// ---------------------------------------------------------------------------
// K1: evt_x = relu(evt_feat @ W_evt + b_evt)     [N_EVT x 64]
// One wave per event row (grid-stride). W column held in 128 VGPRs per lane.
// ---------------------------------------------------------------------------
__global__ __launch_bounds__(256) void k_evt(const float* __restrict__ feat,
                                             const float* __restrict__ W,
                                             const float* __restrict__ b,
                                             float* __restrict__ out, int n) {
    __shared__ float srow[4][128];
    const int lane = threadIdx.x & 63;
    const int w = threadIdx.x >> 6;
    float wreg[128];
#pragma unroll
    for (int j = 0; j < 128; ++j) wreg[j] = W[j * 64 + lane];
    const float bias = b[lane];
    const int wid = blockIdx.x * 4 + w;
    const int nw = gridDim.x * 4;
    for (int e = wid; e < n; e += nw) {
        const float4* rp = (const float4*)(feat + (size_t)e * 128);
        if (lane < 32) ((float4*)srow[w])[lane] = rp[lane];
        const float4* s4 = (const float4*)srow[w];
        float acc = bias;
#pragma unroll
        for (int j4 = 0; j4 < 32; ++j4) {
            float4 x = s4[j4];
            acc = fmaf(x.x, wreg[4 * j4 + 0], acc);
            acc = fmaf(x.y, wreg[4 * j4 + 1], acc);
            acc = fmaf(x.z, wreg[4 * j4 + 2], acc);
            acc = fmaf(x.w, wreg[4 * j4 + 3], acc);
        }
        out[(size_t)e * 64 + lane] = fmaxf(acc, 0.0f);
    }
}

// ---------------------------------------------------------------------------
// K2: loc_x = relu([loc_feat || emb[qid]] @ W_loc + b_loc)   [N_LOC x 64]
// ---------------------------------------------------------------------------
__global__ __launch_bounds__(256) void k_loc(const float* __restrict__ feat,
                                             const int* __restrict__ qid,
                                             const float* __restrict__ emb,
                                             const float* __restrict__ W,
                                             const float* __restrict__ b,
                                             float* __restrict__ out, int n) {
    __shared__ float srow[4][144];
    const int lane = threadIdx.x & 63;
    const int w = threadIdx.x >> 6;
    float wreg[144];
#pragma unroll
    for (int j = 0; j < 144; ++j) wreg[j] = W[j * 64 + lane];
    const float bias = b[lane];
    const int wid = blockIdx.x * 4 + w;
    const int nw = gridDim.x * 4;
    for (int e = wid; e < n; e += nw) {
        const float4* rp = (const float4*)(feat + (size_t)e * 128);
        if (lane < 32) ((float4*)srow[w])[lane] = rp[lane];
        int q = qid[e];
        if (lane < 4)
            ((float4*)(srow[w] + 128))[lane] = ((const float4*)(emb + (size_t)q * 16))[lane];
        const float4* s4 = (const float4*)srow[w];
        float acc = bias;
#pragma unroll
        for (int j4 = 0; j4 < 36; ++j4) {
            float4 x = s4[j4];
            acc = fmaf(x.x, wreg[4 * j4 + 0], acc);
            acc = fmaf(x.y, wreg[4 * j4 + 1], acc);
            acc = fmaf(x.z, wreg[4 * j4 + 2], acc);
            acc = fmaf(x.w, wreg[4 * j4 + 3], acc);
        }
        out[(size_t)e * 64 + lane] = fmaxf(acc, 0.0f);
    }
}

// ---------------------------------------------------------------------------
// k_bin: bucket edges by dst>>8 into fixed-capacity regions.
// Per-block LDS histogram + per-bucket global reservation -> contiguous runs.
// ---------------------------------------------------------------------------
__global__ __launch_bounds__(256) void k_bin(const int* __restrict__ ei,
                                             int* __restrict__ bucket_cnt,
                                             uint2* __restrict__ binned, int n) {
    __shared__ int h[NB];
    __shared__ int base[NB];
    const int t = threadIdx.x;
    for (int i = t; i < NB; i += 256) h[i] = 0;
    __syncthreads();
    const int e0 = blockIdx.x * TILE;
    int src[16], dst[16], rnk[16];
#pragma unroll
    for (int j = 0; j < 16; ++j) {
        int e = e0 + j * 256 + t;
        if (e < n) {
            src[j] = ei[e];
            dst[j] = ei[n + e];
            rnk[j] = atomicAdd(&h[dst[j] >> 8], 1);
        }
    }
    __syncthreads();
    for (int i = t; i < NB; i += 256) {
        int c = h[i];
        base[i] = (c > 0) ? atomicAdd(&bucket_cnt[i], c) : 0;
    }
    __syncthreads();
#pragma unroll
    for (int j = 0; j < 16; ++j) {
        int e = e0 + j * 256 + t;
        if (e < n) {
            int b = dst[j] >> 8;
            int idx = base[b] + rnk[j];
            if (idx < BCAP)  // safety clamp (never expected to trigger)
                binned[(size_t)b * BCAP + idx] = make_uint2((unsigned)src[j], (unsigned)dst[j]);
        }
    }
}

// ---------------------------------------------------------------------------
// k_bscan: exclusive scan of the 391 bucket counts (single block).
// ---------------------------------------------------------------------------
__global__ __launch_bounds__(512) void k_bscan(const int* __restrict__ bucket_cnt,
                                               int* __restrict__ csr_off) {
    __shared__ int sd[512];
    const int t = threadIdx.x;
    int v = (t < NB) ? min(bucket_cnt[t], BCAP) : 0;
    sd[t] = v;
    __syncthreads();
    for (int off = 1; off < 512; off <<= 1) {
        int x = (t >= off) ? sd[t - off] : 0;
        __syncthreads();
        sd[t] += x;
        __syncthreads();
    }
    if (t < NB) csr_off[t] = sd[t] - v;
    if (t == NB - 1) csr_off[NB] = sd[t];
}

// ---------------------------------------------------------------------------
// k_bfill: one block per bucket. LDS degree hist -> LDS scan -> deg/row_ex,
// then scatter csr with LDS cursors (writes confined to ~16KB/block).
// Replaces k_hist + 100K-scan + k_fill.
// ---------------------------------------------------------------------------
__global__ __launch_bounds__(256) void k_bfill(const int* __restrict__ bucket_cnt,
                                               const int* __restrict__ csr_off,
                                               const uint2* __restrict__ binned,
                                               int* __restrict__ deg,
                                               int* __restrict__ row_ex,
                                               int* __restrict__ csr) {
    __shared__ int degl[256];
    __shared__ int sc[256];
    __shared__ int cur[256];
    const int b = blockIdx.x;
    const int t = threadIdx.x;
    const int nb = min(bucket_cnt[b], BCAP);
    const uint2* bin = binned + (size_t)b * BCAP;
    degl[t] = 0;
    __syncthreads();
    for (int i = t; i < nb; i += 256)
        atomicAdd(&degl[bin[i].y & 255], 1);
    __syncthreads();
    const int v = degl[t];
    sc[t] = v;
    __syncthreads();
    for (int off = 1; off < 256; off <<= 1) {
        int x = (t >= off) ? sc[t - off] : 0;
        __syncthreads();
        sc[t] += x;
        __syncthreads();
    }
    const int ex = csr_off[b] + sc[t] - v;
    const int loc = b * 256 + t;
    if (loc < N_LOC) { deg[loc] = v; row_ex[loc] = ex; }
    cur[t] = ex;
    __syncthreads();
    for (int i = t; i < nb; i += 256) {
        uint2 u = bin[i];
        int pos = atomicAdd(&cur[u.y & 255], 1);
        csr[pos] = (int)u.x;
    }
}

// ---------------------------------------------------------------------------
// K4: mean[loc] = (sum over neighbors of evt_x[src]) / max(cnt,1)
// One wave per loc; lane = channel.
// ---------------------------------------------------------------------------
__global__ __launch_bounds__(256) void k_aggr(const float* __restrict__ evt_x,
                                              const int* __restrict__ row_ex,
                                              const int* __restrict__ deg,
                                              const int* __restrict__ csr_src,
                                              float* __restrict__ meanb, int n) {
    const int lane = threadIdx.x & 63;
    const int wid = (blockIdx.x * 256 + threadIdx.x) >> 6;
    if (wid >= n) return;
    const int beg = row_ex[wid];
    const int cnt = deg[wid];
    float acc = 0.0f;
    int i = 0;
    for (; i + 4 <= cnt; i += 4) {
        int s0 = csr_src[beg + i + 0];
        int s1 = csr_src[beg + i + 1];
        int s2 = csr_src[beg + i + 2];
        int s3 = csr_src[beg + i + 3];
        float a0 = evt_x[(size_t)s0 * 64 + lane];
        float a1 = evt_x[(size_t)s1 * 64 + lane];
        float a2 = evt_x[(size_t)s2 * 64 + lane];
        float a3 = evt_x[(size_t)s3 * 64 + lane];
        acc += a0 + a1 + a2 + a3;
    }
    for (; i < cnt; ++i) acc += evt_x[(size_t)csr_src[beg + i] * 64 + lane];
    float c = (cnt > 0) ? (float)cnt : 1.0f;
    meanb[(size_t)wid * 64 + lane] = acc / c;
}

// ---------------------------------------------------------------------------
// K5: x2 = relu(mean @ W_l + b_l + loc_x @ W_r); h = relu(x2 @ W_h1 + b_h1);
//     out = h @ W_h2 + b_h2
// ---------------------------------------------------------------------------
__global__ __launch_bounds__(256) void k_comb(const float* __restrict__ meanb,
                                              const float* __restrict__ locx,
                                              const float* __restrict__ W_l,
                                              const float* __restrict__ b_l,
                                              const float* __restrict__ W_r,
                                              const float* __restrict__ W_h1,
                                              const float* __restrict__ b_h1,
                                              const float* __restrict__ W_h2,
                                              const float* __restrict__ b_h2,
                                              float* __restrict__ out, int n) {
    __shared__ float sWh1[64 * 32];
    __shared__ float sWh2[32];
    __shared__ float sm[4][64];
    __shared__ float sx[4][64];
    const int t = threadIdx.x;
    for (int i = t; i < 2048; i += 256) sWh1[i] = W_h1[i];
    if (t < 32) sWh2[t] = W_h2[t];
    const int lane = t & 63;
    const int w = t >> 6;
    float wl[64], wr[64];
#pragma unroll
    for (int j = 0; j < 64; ++j) {
        wl[j] = W_l[j * 64 + lane];
        wr[j] = W_r[j * 64 + lane];
    }
    const float bl = b_l[lane];
    const int kk = lane & 31;
    const float bh1 = b_h1[kk];
    const float bh2 = b_h2[0];
    __syncthreads();
    const int wid0 = blockIdx.x * 4 + w;
    const int nw = gridDim.x * 4;
    for (int loc = wid0; loc < n; loc += nw) {
        float mv = meanb[(size_t)loc * 64 + lane];
        float xv = locx[(size_t)loc * 64 + lane];
        sm[w][lane] = mv;
        sx[w][lane] = xv;
        const float4* m4 = (const float4*)sm[w];
        const float4* x4 = (const float4*)sx[w];
        float o = bl;
#pragma unroll
        for (int j4 = 0; j4 < 16; ++j4) {
            float4 a = m4[j4];
            float4 c = x4[j4];
            o = fmaf(a.x, wl[4 * j4 + 0], o); o = fmaf(c.x, wr[4 * j4 + 0], o);
            o = fmaf(a.y, wl[4 * j4 + 1], o); o = fmaf(c.y, wr[4 * j4 + 1], o);
            o = fmaf(a.z, wl[4 * j4 + 2], o); o = fmaf(c.z, wr[4 * j4 + 2], o);
            o = fmaf(a.w, wl[4 * j4 + 3], o); o = fmaf(c.w, wr[4 * j4 + 3], o);
        }
        o = fmaxf(o, 0.0f);
        sx[w][lane] = o;  // same-wave LDS ops are in-order: safe without barrier
        float hv = bh1;
#pragma unroll
        for (int j4 = 0; j4 < 16; ++j4) {
            float4 a = x4[j4];
            hv = fmaf(a.x, sWh1[(4 * j4 + 0) * 32 + kk], hv);
            hv = fmaf(a.y, sWh1[(4 * j4 + 1) * 32 + kk], hv);
            hv = fmaf(a.z, sWh1[(4 * j4 + 2) * 32 + kk], hv);
            hv = fmaf(a.w, sWh1[(4 * j4 + 3) * 32 + kk], hv);
        }
        hv = fmaxf(hv, 0.0f) * sWh2[kk];
#pragma unroll
        for (int m = 16; m >= 1; m >>= 1) hv += __shfl_xor(hv, m);
        if (lane == 0) out[loc] = hv + bh2;
    }
}

// ---------------------------------------------------------------------------
extern "C" void kernel_launch(void* const* d_in, const int* in_sizes, int n_in,
                              void* d_out, int out_size, void* d_ws, size_t ws_size,
                              hipStream_t stream) {
    const float* loc_feat = (const float*)d_in[0];
    const float* evt_feat = (const float*)d_in[1];
    const int*   qid      = (const int*)d_in[2];
    const int*   ei       = (const int*)d_in[3];
    const float* emb      = (const float*)d_in[4];
    const float* W_loc    = (const float*)d_in[5];
    const float* b_loc    = (const float*)d_in[6];
    const float* W_evt    = (const float*)d_in[7];
    const float* b_evt    = (const float*)d_in[8];
    const float* W_l      = (const float*)d_in[9];
    const float* b_l      = (const float*)d_in[10];
    const float* W_r      = (const float*)d_in[11];
    const float* W_h1     = (const float*)d_in[12];
    const float* b_h1     = (const float*)d_in[13];
    const float* W_h2     = (const float*)d_in[14];
    const float* b_h2     = (const float*)d_in[15];
    float* out = (float*)d_out;

    char* ws = (char*)d_ws;
    size_t off = 0;
    auto alloc = [&](size_t bytes) -> void* {
        void* p = ws + off;
        off += (bytes + 255) & ~(size_t)255;
        return p;
    };
    float* evt_x    = (float*)alloc((size_t)N_EVT * 64 * 4);
    float* loc_x    = (float*)alloc((size_t)N_LOC * 64 * 4);
    float* meanb    = (float*)alloc((size_t)N_LOC * 64 * 4);   // aliased with binned
    int*   deg      = (int*)alloc((size_t)N_LOC * 4);
    int*   row_ex   = (int*)alloc((size_t)(N_LOC + 1) * 4);
    int*   csr      = (int*)alloc((size_t)N_EDGE * 4);
    int*   bucket_cnt = (int*)alloc((size_t)NB * 4);
    int*   csr_off  = (int*)alloc((size_t)(NB + 1) * 4);
    uint2* binned   = (uint2*)meanb;  // 391*5120*8B = 16.0MB <= 25.6MB, disjoint lifetime
    (void)ws_size; (void)in_sizes; (void)n_in; (void)out_size;

    hipMemsetAsync(bucket_cnt, 0, (size_t)NB * 4, stream);

    k_evt<<<768, 256, 0, stream>>>(evt_feat, W_evt, b_evt, evt_x, N_EVT);
    k_loc<<<768, 256, 0, stream>>>(loc_feat, qid, emb, W_loc, b_loc, loc_x, N_LOC);
    k_bin<<<(N_EDGE + TILE - 1) / TILE, 256, 0, stream>>>(ei, bucket_cnt, binned, N_EDGE);
    k_bscan<<<1, 512, 0, stream>>>(bucket_cnt, csr_off);
    k_bfill<<<NB, 256, 0, stream>>>(bucket_cnt, csr_off, binned, deg, row_ex, csr);
    k_aggr<<<N_LOC / 4, 256, 0, stream>>>(evt_x, row_ex, deg, csr, meanb, N_LOC);
    k_comb<<<768, 256, 0, stream>>>(meanb, loc_x, W_l, b_l, W_r, W_h1, b_h1, W_h2, b_h2, out, N_LOC);
}